// Round 5
// baseline (5503.741 us; speedup 1.0000x reference)
//
#include <hip/hip_runtime.h>

// MoE block: B=4,S=2048 -> T=8192 tokens, D=2048, F=8192, E=8, K=2
#define T_TOK 8192
#define DIM   2048
#define FFN   8192
#define NE    8
#define TOPK  2

typedef unsigned short ushort_t;
typedef unsigned short ushort8  __attribute__((ext_vector_type(8)));
typedef unsigned short ushort4v __attribute__((ext_vector_type(4)));
typedef short bf16x8 __attribute__((ext_vector_type(8)));
typedef float f32x4  __attribute__((ext_vector_type(4)));

__device__ __forceinline__ ushort_t f2bf(float f) {
  unsigned int u = __float_as_uint(f);
  u += 0x7FFFu + ((u >> 16) & 1u);   // RNE
  return (ushort_t)(u >> 16);
}
__device__ __forceinline__ float bf2f(ushort_t u) {
  return __uint_as_float(((unsigned int)u) << 16);
}

// async global->LDS, 16B per lane. LDS dest wave-uniform base; HW adds lane*16.
__device__ __forceinline__ void gload16(const void* g, void* l) {
  __builtin_amdgcn_global_load_lds((const __attribute__((address_space(1))) void*)g,
                                   (__attribute__((address_space(3))) void*)l, 16, 0, 0);
}

// exact-erf GELU via Abramowitz-Stegun 7.1.26 (|err| <= 1.5e-7)
__device__ __forceinline__ float gelu_exact(float v) {
  float s = v * 0.70710678118654752f;
  float a = fabsf(s);
  float t = __builtin_amdgcn_rcpf(1.0f + 0.3275911f * a);
  float p = t * (0.254829592f +
            t * (-0.284496736f +
            t * (1.421413741f +
            t * (-1.453152027f +
            t * 1.061405429f))));
  float er = 1.0f - p * __expf(-a * a);
  er = copysignf(er, s);
  return 0.5f * v * (1.0f + er);
}

// ---------------- cast x -> bf16 ----------------
__global__ void k_cast(const float* __restrict__ x, ushort_t* __restrict__ xbf) {
  int i = blockIdx.x * blockDim.x + threadIdx.x;
  float4 v = reinterpret_cast<const float4*>(x)[i];
  ushort4v o;
  o.x = f2bf(v.x); o.y = f2bf(v.y); o.z = f2bf(v.z); o.w = f2bf(v.w);
  reinterpret_cast<ushort4v*>(xbf)[i] = o;
}

// ---------------- weight convert+transpose: fp32 [R][C] -> bf16 [C][R] ----------------
#define TT 64
__global__ __launch_bounds__(256) void k_wcvt(const float* __restrict__ in,
                                              ushort_t* __restrict__ outp, int R, int C) {
  __shared__ ushort_t t[TT][TT + 8];
  int e = blockIdx.z;
  const float* src = in + (size_t)e * R * C;
  ushort_t* dst = outp + (size_t)e * R * C;
  int r0 = blockIdx.y * TT, c0 = blockIdx.x * TT;
  int tid = threadIdx.x;
  int rr = tid >> 4;
  int c4 = tid & 15;
#pragma unroll
  for (int i = 0; i < 4; i++) {
    int r = rr + i * 16;
    float4 v = *reinterpret_cast<const float4*>(src + (size_t)(r0 + r) * C + c0 + c4 * 4);
    ushort4v p;
    p.x = f2bf(v.x); p.y = f2bf(v.y); p.z = f2bf(v.z); p.w = f2bf(v.w);
    *reinterpret_cast<ushort4v*>(&t[r][c4 * 4]) = p;
  }
  __syncthreads();
  int c = tid >> 2, rs = tid & 3;
  ushort_t tmp[16];
#pragma unroll
  for (int i = 0; i < 16; i++) tmp[i] = t[rs * 16 + i][c];
  ushort8 v0, v1;
#pragma unroll
  for (int i = 0; i < 8; i++) { v0[i] = tmp[i]; v1[i] = tmp[8 + i]; }
  ushort_t* drow = dst + (size_t)(c0 + c) * R + r0 + rs * 16;
  *reinterpret_cast<ushort8*>(drow) = v0;
  *reinterpret_cast<ushort8*>(drow + 8) = v1;
}

// ---------------- router ----------------
__global__ __launch_bounds__(256) void k_router(
    const float* __restrict__ x, const float* __restrict__ rw,
    int* __restrict__ tidx, float* __restrict__ twt, int* __restrict__ counts) {
  int t = blockIdx.x;
  int tid = threadIdx.x;
  int lane = tid & 63, wave = tid >> 6;
  float acc[NE];
#pragma unroll
  for (int e = 0; e < NE; e++) acc[e] = 0.f;
  const float* xr = x + (size_t)t * DIM;
  for (int d = tid; d < DIM; d += 256) {
    float xv = xr[d];
    const float* r = rw + d * NE;
#pragma unroll
    for (int e = 0; e < NE; e++) acc[e] += xv * r[e];
  }
  __shared__ float wsum[4][NE];
#pragma unroll
  for (int e = 0; e < NE; e++) {
    float v = acc[e];
#pragma unroll
    for (int off = 32; off > 0; off >>= 1) v += __shfl_down(v, off);
    if (lane == 0) wsum[wave][e] = v;
  }
  __syncthreads();
  if (tid == 0) {
    float lg[NE];
#pragma unroll
    for (int e = 0; e < NE; e++) lg[e] = wsum[0][e] + wsum[1][e] + wsum[2][e] + wsum[3][e];
    int i0 = 0; float v0 = lg[0];
#pragma unroll
    for (int e = 1; e < NE; e++) if (lg[e] > v0) { v0 = lg[e]; i0 = e; }
    int i1 = -1; float v1 = -3.4e38f;
#pragma unroll
    for (int e = 0; e < NE; e++) if (e != i0 && lg[e] > v1) { v1 = lg[e]; i1 = e; }
    float e1 = expf(v1 - v0);
    float s = 1.f + e1;
    tidx[t * 2 + 0] = i0; tidx[t * 2 + 1] = i1;
    twt[t * 2 + 0] = 1.f / s; twt[t * 2 + 1] = e1 / s;
    atomicAdd(&counts[i0], 1);
    atomicAdd(&counts[i1], 1);
  }
}

__global__ void k_scan(const int* __restrict__ counts, int* __restrict__ offsets) {
  if (threadIdx.x == 0) {
    int s = 0;
    for (int e = 0; e < NE; e++) { offsets[e] = s; s += counts[e]; }
    offsets[NE] = s;
  }
}

__global__ void k_fill(const int* __restrict__ tidx, const float* __restrict__ twt,
                       const int* __restrict__ offsets, int* __restrict__ cursors,
                       int* __restrict__ ltok, float* __restrict__ lwt, int* __restrict__ ppos) {
  int t = blockIdx.x * blockDim.x + threadIdx.x;
  if (t >= T_TOK) return;
#pragma unroll
  for (int k = 0; k < TOPK; k++) {
    int e = tidx[t * 2 + k];
    int pos = atomicAdd(&cursors[e], 1);
    int p = offsets[e] + pos;
    ltok[p] = t;
    lwt[p] = twt[t * 2 + k];
    ppos[t * 2 + k] = p;
  }
}

// ============ 256x256 GEMMs, BK=32, 8 waves, counted-vmcnt pipeline (T4) ============
// LDS: [buf][A/B][half][128*32] bf16 = 64 KiB. Row stride 64B = 16 banks ->
// fragment reads (16 lanes x 16 rows, fixed 16B chunk) hit the b128 floor: no swizzle.
#define GBM 256
#define GBN 256
#define GBK 32

template <int NT>
__device__ __forceinline__ void gemm_pipe(const ushort_t* a0, const ushort_t* a1,
                                          const ushort_t* b0, const ushort_t* b1,
                                          f32x4 (&acc)[8][4]) {
  __shared__ __align__(16) ushort_t lds[2][2][2][128 * 32];
  int tid = threadIdx.x;
  int wid = tid >> 6, lane = tid & 63;
  int wm = wid >> 2, wn = wid & 3;
  int lm = lane & 15, lg = lane >> 4;

  const ushort_t* aptr[2] = {a0, a1};
  const ushort_t* bptr[2] = {b0, b1};

  auto STAGE = [&](int b) {
#pragma unroll
    for (int h = 0; h < 2; h++) {
      gload16(aptr[h], &lds[b][0][h][wid * 512]);
      gload16(bptr[h], &lds[b][1][h][wid * 512]);
      aptr[h] += GBK; bptr[h] += GBK;
    }
  };
  auto COMPUTE = [&](int b) {
    const ushort_t* Ah = &lds[b][0][wm][0];
    const ushort_t* Bh = &lds[b][1][wn >> 1][0];
    bf16x8 af[8], bv[4];
#pragma unroll
    for (int m = 0; m < 8; m++)
      af[m] = *reinterpret_cast<const bf16x8*>(&Ah[(m * 16 + lm) * 32 + lg * 8]);
#pragma unroll
    for (int n = 0; n < 4; n++)
      bv[n] = *reinterpret_cast<const bf16x8*>(&Bh[((wn & 1) * 64 + n * 16 + lm) * 32 + lg * 8]);
#pragma unroll
    for (int m = 0; m < 8; m++)
#pragma unroll
      for (int n = 0; n < 4; n++)
        acc[m][n] = __builtin_amdgcn_mfma_f32_16x16x32_bf16(af[m], bv[n], acc[m][n], 0, 0, 0);
  };

  STAGE(0);
  int cur = 0;
  for (int t = 0; t < NT - 1; ++t) {
    STAGE(cur ^ 1);
    asm volatile("s_waitcnt vmcnt(4)" ::: "memory");   // prev tile's 4 loads done
    __builtin_amdgcn_sched_barrier(0);
    __builtin_amdgcn_s_barrier();
    __builtin_amdgcn_sched_barrier(0);
    COMPUTE(cur);
    asm volatile("s_waitcnt lgkmcnt(0)" ::: "memory"); // all ds_reads of this buf done
    __builtin_amdgcn_sched_barrier(0);
    __builtin_amdgcn_s_barrier();
    __builtin_amdgcn_sched_barrier(0);
    cur ^= 1;
  }
  asm volatile("s_waitcnt vmcnt(0)" ::: "memory");
  __builtin_amdgcn_sched_barrier(0);
  __builtin_amdgcn_s_barrier();
  __builtin_amdgcn_sched_barrier(0);
  COMPUTE(cur);
}

// GEMM1: H[p,f] = gelu( gather(x)[p,:] @ w1t[e]^T + b1[e] )   w1t: [F][D] bf16
// grid: x = row-tile (consecutive blocks share the B panel), y = col-tile, z = expert
__global__ __launch_bounds__(512, 2) void k_gemm1(
    const ushort_t* __restrict__ xbf, const ushort_t* __restrict__ w1t, const float* __restrict__ b1,
    const int* __restrict__ counts, const int* __restrict__ offsets,
    const int* __restrict__ ltok, ushort_t* __restrict__ H) {
  int e = blockIdx.z;
  int cnt = counts[e];
  int row0 = blockIdx.x * GBM;
  if (row0 >= cnt) return;
  int base = offsets[e];
  int col0 = blockIdx.y * GBN;
  const ushort_t* Bt = w1t + (size_t)e * DIM * FFN;

  int tid = threadIdx.x;
  int hrow = tid >> 2, slot = tid & 3;
  const ushort_t* aptr[2]; const ushort_t* bptr[2];
#pragma unroll
  for (int h = 0; h < 2; h++) {
    int R = h * 128 + hrow;
    int ar = min(row0 + R, cnt - 1);
    aptr[h] = xbf + (size_t)ltok[base + ar] * DIM + slot * 8;
    bptr[h] = Bt + (size_t)(col0 + R) * DIM + slot * 8;
  }

  f32x4 acc[8][4];
#pragma unroll
  for (int m = 0; m < 8; m++)
#pragma unroll
    for (int n = 0; n < 4; n++) acc[m][n] = (f32x4){0.f, 0.f, 0.f, 0.f};

  gemm_pipe<DIM / GBK>(aptr[0], aptr[1], bptr[0], bptr[1], acc);

  int wid = tid >> 6, lane = tid & 63;
  int wm = wid >> 2, wn = wid & 3;
  int lm = lane & 15, lg = lane >> 4;
#pragma unroll
  for (int m = 0; m < 8; m++) {
#pragma unroll
    for (int n = 0; n < 4; n++) {
      int f = col0 + wn * 64 + n * 16 + lm;
      float bias = b1[e * FFN + f];
#pragma unroll
      for (int r = 0; r < 4; r++) {
        int row = row0 + wm * 128 + m * 16 + lg * 4 + r;
        if (row < cnt) {
          float v = acc[m][n][r] + bias;
          H[(size_t)(base + row) * FFN + f] = f2bf(gelu_exact(v));
        }
      }
    }
  }
}

// GEMM2: contrib[p,d] = cw[p] * ( H[p,:] @ w2t[e]^T + b2[e] )   w2t: [D][F] bf16
__global__ __launch_bounds__(512, 2) void k_gemm2(
    const ushort_t* __restrict__ H, const ushort_t* __restrict__ w2t, const float* __restrict__ b2,
    const int* __restrict__ counts, const int* __restrict__ offsets,
    const float* __restrict__ lwt, ushort_t* __restrict__ contrib) {
  int e = blockIdx.z;
  int cnt = counts[e];
  int row0 = blockIdx.x * GBM;
  if (row0 >= cnt) return;
  int base = offsets[e];
  int col0 = blockIdx.y * GBN;
  const ushort_t* Bt = w2t + (size_t)e * DIM * FFN;

  int tid = threadIdx.x;
  int hrow = tid >> 2, slot = tid & 3;
  const ushort_t* aptr[2]; const ushort_t* bptr[2];
#pragma unroll
  for (int h = 0; h < 2; h++) {
    int R = h * 128 + hrow;
    int ar = min(row0 + R, cnt - 1);
    aptr[h] = H + (size_t)(base + ar) * FFN + slot * 8;
    bptr[h] = Bt + (size_t)(col0 + R) * FFN + slot * 8;
  }

  f32x4 acc[8][4];
#pragma unroll
  for (int m = 0; m < 8; m++)
#pragma unroll
    for (int n = 0; n < 4; n++) acc[m][n] = (f32x4){0.f, 0.f, 0.f, 0.f};

  gemm_pipe<FFN / GBK>(aptr[0], aptr[1], bptr[0], bptr[1], acc);

  int wid = tid >> 6, lane = tid & 63;
  int wm = wid >> 2, wn = wid & 3;
  int lm = lane & 15, lg = lane >> 4;
#pragma unroll
  for (int m = 0; m < 8; m++) {
#pragma unroll
    for (int n = 0; n < 4; n++) {
      int d = col0 + wn * 64 + n * 16 + lm;
      float bias = b2[e * DIM + d];
#pragma unroll
      for (int r = 0; r < 4; r++) {
        int row = row0 + wm * 128 + m * 16 + lg * 4 + r;
        if (row < cnt) {
          float v = (acc[m][n][r] + bias) * lwt[base + row];
          contrib[(size_t)(base + row) * DIM + d] = f2bf(v);
        }
      }
    }
  }
}

// ---------------- combine: out = x + contrib[p0] + contrib[p1] ----------------
__global__ void k_combine(const float* __restrict__ x, const ushort_t* __restrict__ contrib,
                          const int* __restrict__ ppos, float* __restrict__ out) {
  int i = blockIdx.x * blockDim.x + threadIdx.x;
  int t = i / (DIM / 4);
  int dq = i % (DIM / 4);
  int p0 = ppos[t * 2 + 0], p1 = ppos[t * 2 + 1];
  float4 xv = reinterpret_cast<const float4*>(x)[i];
  ushort4v c0 = reinterpret_cast<const ushort4v*>(contrib + (size_t)p0 * DIM)[dq];
  ushort4v c1 = reinterpret_cast<const ushort4v*>(contrib + (size_t)p1 * DIM)[dq];
  float4 o;
  o.x = xv.x + bf2f(c0.x) + bf2f(c1.x);
  o.y = xv.y + bf2f(c0.y) + bf2f(c1.y);
  o.z = xv.z + bf2f(c0.z) + bf2f(c1.z);
  o.w = xv.w + bf2f(c0.w) + bf2f(c1.w);
  reinterpret_cast<float4*>(out)[i] = o;
}

extern "C" void kernel_launch(void* const* d_in, const int* in_sizes, int n_in,
                              void* d_out, int out_size, void* d_ws, size_t ws_size,
                              hipStream_t stream) {
  const float* x  = (const float*)d_in[0];
  const float* rw = (const float*)d_in[1];
  const float* w1 = (const float*)d_in[2];
  const float* b1 = (const float*)d_in[3];
  const float* w2 = (const float*)d_in[4];
  const float* b2 = (const float*)d_in[5];
  float* out = (float*)d_out;
  char* ws = (char*)d_ws;

  const size_t MB = 1u << 20;
  int*   counts  = (int*)(ws);
  int*   offsets = (int*)(ws + 64);
  int*   cursors = (int*)(ws + 128);
  int*   tidx    = (int*)(ws + 1 * MB);
  float* twt     = (float*)(ws + 2 * MB);
  int*   ltok    = (int*)(ws + 3 * MB);
  float* lwt     = (float*)(ws + 4 * MB);
  int*   ppos    = (int*)(ws + 5 * MB);
  // overlaid big buffers (lifetimes disjoint where they overlap):
  ushort_t* xbf     = (ushort_t*)(ws + 8 * MB);     // 32 MB, live cast..gemm1
  ushort_t* contrib = (ushort_t*)(ws + 8 * MB);     // 64 MB, live gemm2..combine (xbf dead)
  ushort_t* Hbuf    = (ushort_t*)(ws + 72 * MB);    // 256 MB, live gemm1..gemm2
  ushort_t* w1t     = (ushort_t*)(ws + 328 * MB);   // 256 MB, live wcvt1..gemm1
  ushort_t* w2t     = (ushort_t*)(ws + 328 * MB);   // 256 MB, live wcvt2..gemm2 (after gemm1)
  const size_t NEED = 584 * MB;
  if (ws_size < NEED) {
    hipMemsetAsync(d_out, 0, (size_t)out_size * sizeof(float), stream);
    return;
  }

  hipMemsetAsync(ws, 0, 256, stream);  // counts + cursors
  k_cast<<<dim3((T_TOK * (size_t)DIM / 4) / 256), 256, 0, stream>>>(x, xbf);
  k_router<<<T_TOK, 256, 0, stream>>>(x, rw, tidx, twt, counts);
  k_scan<<<1, 64, 0, stream>>>(counts, offsets);
  k_fill<<<T_TOK / 256, 256, 0, stream>>>(tidx, twt, offsets, cursors, ltok, lwt, ppos);
  // w1: [E][D][F] fp32 -> w1t [E][F][D] bf16
  k_wcvt<<<dim3(FFN / TT, DIM / TT, NE), 256, 0, stream>>>(w1, w1t, DIM, FFN);
  k_gemm1<<<dim3(T_TOK / GBM, FFN / GBN, NE), 512, 0, stream>>>(xbf, w1t, b1, counts, offsets, ltok, Hbuf);
  // w2: [E][F][D] fp32 -> w2t [E][D][F] bf16  (after gemm1; reuses w1t region)
  k_wcvt<<<dim3(DIM / TT, FFN / TT, NE), 256, 0, stream>>>(w2, w2t, FFN, DIM);
  k_gemm2<<<dim3(T_TOK / GBM, DIM / GBN, NE), 512, 0, stream>>>(Hbuf, w2t, b2, counts, offsets, lwt, contrib);
  k_combine<<<dim3((T_TOK * (size_t)DIM / 4) / 256), 256, 0, stream>>>(x, contrib, ppos, out);
}

// Round 6
// 2186.594 us; speedup vs baseline: 2.5170x; 2.5170x over previous
//
#include <hip/hip_runtime.h>

// MoE block: B=4,S=2048 -> T=8192 tokens, D=2048, F=8192, E=8, K=2
#define T_TOK 8192
#define DIM   2048
#define FFN   8192
#define NE    8
#define TOPK  2

typedef unsigned short ushort_t;
typedef unsigned short ushort8  __attribute__((ext_vector_type(8)));
typedef unsigned short ushort4v __attribute__((ext_vector_type(4)));
typedef short bf16x8 __attribute__((ext_vector_type(8)));
typedef float f32x4  __attribute__((ext_vector_type(4)));

__device__ __forceinline__ ushort_t f2bf(float f) {
  unsigned int u = __float_as_uint(f);
  u += 0x7FFFu + ((u >> 16) & 1u);   // RNE
  return (ushort_t)(u >> 16);
}
__device__ __forceinline__ float bf2f(ushort_t u) {
  return __uint_as_float(((unsigned int)u) << 16);
}

// async global->LDS, 16B per lane. LDS dest wave-uniform base; HW adds lane*16.
__device__ __forceinline__ void gload16(const void* g, void* l) {
  __builtin_amdgcn_global_load_lds((const __attribute__((address_space(1))) void*)g,
                                   (__attribute__((address_space(3))) void*)l, 16, 0, 0);
}

// exact-erf GELU via Abramowitz-Stegun 7.1.26 (|err| <= 1.5e-7)
__device__ __forceinline__ float gelu_exact(float v) {
  float s = v * 0.70710678118654752f;
  float a = fabsf(s);
  float t = __builtin_amdgcn_rcpf(1.0f + 0.3275911f * a);
  float p = t * (0.254829592f +
            t * (-0.284496736f +
            t * (1.421413741f +
            t * (-1.453152027f +
            t * 1.061405429f))));
  float er = 1.0f - p * __expf(-a * a);
  er = copysignf(er, s);
  return 0.5f * v * (1.0f + er);
}

// ---------------- cast x -> bf16 ----------------
__global__ void k_cast(const float* __restrict__ x, ushort_t* __restrict__ xbf) {
  int i = blockIdx.x * blockDim.x + threadIdx.x;
  float4 v = reinterpret_cast<const float4*>(x)[i];
  ushort4v o;
  o.x = f2bf(v.x); o.y = f2bf(v.y); o.z = f2bf(v.z); o.w = f2bf(v.w);
  reinterpret_cast<ushort4v*>(xbf)[i] = o;
}

// ---------------- weight convert+transpose: fp32 [R][C] -> bf16 [C][R] ----------------
#define TT 64
__global__ __launch_bounds__(256) void k_wcvt(const float* __restrict__ in,
                                              ushort_t* __restrict__ outp, int R, int C) {
  __shared__ ushort_t t[TT][TT + 8];
  int e = blockIdx.z;
  const float* src = in + (size_t)e * R * C;
  ushort_t* dst = outp + (size_t)e * R * C;
  int r0 = blockIdx.y * TT, c0 = blockIdx.x * TT;
  int tid = threadIdx.x;
  int rr = tid >> 4;
  int c4 = tid & 15;
#pragma unroll
  for (int i = 0; i < 4; i++) {
    int r = rr + i * 16;
    float4 v = *reinterpret_cast<const float4*>(src + (size_t)(r0 + r) * C + c0 + c4 * 4);
    ushort4v p;
    p.x = f2bf(v.x); p.y = f2bf(v.y); p.z = f2bf(v.z); p.w = f2bf(v.w);
    *reinterpret_cast<ushort4v*>(&t[r][c4 * 4]) = p;
  }
  __syncthreads();
  int c = tid >> 2, rs = tid & 3;
  ushort_t tmp[16];
#pragma unroll
  for (int i = 0; i < 16; i++) tmp[i] = t[rs * 16 + i][c];
  ushort8 v0, v1;
#pragma unroll
  for (int i = 0; i < 8; i++) { v0[i] = tmp[i]; v1[i] = tmp[8 + i]; }
  ushort_t* drow = dst + (size_t)(c0 + c) * R + r0 + rs * 16;
  *reinterpret_cast<ushort8*>(drow) = v0;
  *reinterpret_cast<ushort8*>(drow + 8) = v1;
}

// ---------------- router ----------------
__global__ __launch_bounds__(256) void k_router(
    const float* __restrict__ x, const float* __restrict__ rw,
    int* __restrict__ tidx, float* __restrict__ twt, int* __restrict__ counts) {
  int t = blockIdx.x;
  int tid = threadIdx.x;
  int lane = tid & 63, wave = tid >> 6;
  float acc[NE];
#pragma unroll
  for (int e = 0; e < NE; e++) acc[e] = 0.f;
  const float* xr = x + (size_t)t * DIM;
  for (int d = tid; d < DIM; d += 256) {
    float xv = xr[d];
    const float* r = rw + d * NE;
#pragma unroll
    for (int e = 0; e < NE; e++) acc[e] += xv * r[e];
  }
  __shared__ float wsum[4][NE];
#pragma unroll
  for (int e = 0; e < NE; e++) {
    float v = acc[e];
#pragma unroll
    for (int off = 32; off > 0; off >>= 1) v += __shfl_down(v, off);
    if (lane == 0) wsum[wave][e] = v;
  }
  __syncthreads();
  if (tid == 0) {
    float lg[NE];
#pragma unroll
    for (int e = 0; e < NE; e++) lg[e] = wsum[0][e] + wsum[1][e] + wsum[2][e] + wsum[3][e];
    int i0 = 0; float v0 = lg[0];
#pragma unroll
    for (int e = 1; e < NE; e++) if (lg[e] > v0) { v0 = lg[e]; i0 = e; }
    int i1 = -1; float v1 = -3.4e38f;
#pragma unroll
    for (int e = 0; e < NE; e++) if (e != i0 && lg[e] > v1) { v1 = lg[e]; i1 = e; }
    float e1 = expf(v1 - v0);
    float s = 1.f + e1;
    tidx[t * 2 + 0] = i0; tidx[t * 2 + 1] = i1;
    twt[t * 2 + 0] = 1.f / s; twt[t * 2 + 1] = e1 / s;
    atomicAdd(&counts[i0], 1);
    atomicAdd(&counts[i1], 1);
  }
}

__global__ void k_scan(const int* __restrict__ counts, int* __restrict__ offsets) {
  if (threadIdx.x == 0) {
    int s = 0;
    for (int e = 0; e < NE; e++) { offsets[e] = s; s += counts[e]; }
    offsets[NE] = s;
  }
}

__global__ void k_fill(const int* __restrict__ tidx, const float* __restrict__ twt,
                       const int* __restrict__ offsets, int* __restrict__ cursors,
                       int* __restrict__ ltok, float* __restrict__ lwt, int* __restrict__ ppos) {
  int t = blockIdx.x * blockDim.x + threadIdx.x;
  if (t >= T_TOK) return;
#pragma unroll
  for (int k = 0; k < TOPK; k++) {
    int e = tidx[t * 2 + k];
    int pos = atomicAdd(&cursors[e], 1);
    int p = offsets[e] + pos;
    ltok[p] = t;
    lwt[p] = twt[t * 2 + k];
    ppos[t * 2 + k] = p;
  }
}

// ---------------- m97-style GEMMs (round-2 proven) + XCD-chunked swizzle ----------------
#define BM 128
#define BN 128
#define BK 32

// XCD-chunked bijective swizzle (m204-style; nwg divisible by 8).
// HW assigns linear block b -> XCD b%8; remap so each XCD owns a CONTIGUOUS
// chunk of work ids. Within a chunk, work id = row-tile fastest -> all row
// blocks sharing a B col-panel run on ONE XCD (panel fetched once per XCD).
__device__ __forceinline__ void xcd_decode(int lin, int nwg, int nx, int& xt, int& yt) {
  int q = nwg >> 3;
  int w = (lin & 7) * q + (lin >> 3);
  xt = w % nx;   // row tile (fastest within chunk)
  yt = w / nx;   // col tile
}

// GEMM1: H[p,f] = gelu( gather(x)[p,:] @ w1t[e]^T + b1[e] )   w1t: [F][D] bf16
__global__ __launch_bounds__(256) void k_gemm1(
    const ushort_t* __restrict__ xbf, const ushort_t* __restrict__ w1t, const float* __restrict__ b1,
    const int* __restrict__ counts, const int* __restrict__ offsets,
    const int* __restrict__ ltok, ushort_t* __restrict__ H) {
  int e = blockIdx.z;
  int cnt = counts[e];
  int xt, yt;
  xcd_decode(blockIdx.x, (T_TOK / BM) * (FFN / BN), T_TOK / BM, xt, yt);
  int row0 = xt * BM;
  if (row0 >= cnt) return;
  int base = offsets[e];
  int col0 = yt * BN;
  const ushort_t* Bt = w1t + (size_t)e * DIM * FFN;

  __shared__ __align__(16) ushort_t As[BM * BK];   // linear [128][32]
  __shared__ __align__(16) ushort_t Bs[BM * BK];

  int tid = threadIdx.x;
  int wave = tid >> 6, lane = tid & 63;
  int wm = wave >> 1, wn = wave & 1;
  int lm = lane & 15, lg = lane >> 4;

  int srow = tid >> 2, seg = tid & 3;
  const ushort_t* asrc[2]; const ushort_t* bsrc[2];
#pragma unroll
  for (int j = 0; j < 2; j++) {
    int ar = min(row0 + j * 64 + srow, cnt - 1);
    asrc[j] = xbf + (size_t)ltok[base + ar] * DIM + seg * 8;
    bsrc[j] = Bt + (size_t)(col0 + j * 64 + srow) * DIM + seg * 8;
  }
  f32x4 acc[4][4];
#pragma unroll
  for (int m = 0; m < 4; m++)
#pragma unroll
    for (int n = 0; n < 4; n++) acc[m][n] = (f32x4){0.f, 0.f, 0.f, 0.f};

  for (int k0 = 0; k0 < DIM; k0 += BK) {
#pragma unroll
    for (int j = 0; j < 2; j++) {
      gload16(asrc[j] + k0, &As[(j * 256 + wave * 64) * 8]);
      gload16(bsrc[j] + k0, &Bs[(j * 256 + wave * 64) * 8]);
    }
    __syncthreads();   // compiler drains vmcnt before barrier
    bf16x8 af[4], bfv[4];
#pragma unroll
    for (int m = 0; m < 4; m++)
      af[m] = *reinterpret_cast<const bf16x8*>(&As[(wm * 64 + m * 16 + lm) * BK + lg * 8]);
#pragma unroll
    for (int n = 0; n < 4; n++)
      bfv[n] = *reinterpret_cast<const bf16x8*>(&Bs[(wn * 64 + n * 16 + lm) * BK + lg * 8]);
#pragma unroll
    for (int m = 0; m < 4; m++)
#pragma unroll
      for (int n = 0; n < 4; n++)
        acc[m][n] = __builtin_amdgcn_mfma_f32_16x16x32_bf16(af[m], bfv[n], acc[m][n], 0, 0, 0);
    __syncthreads();
  }
#pragma unroll
  for (int m = 0; m < 4; m++) {
#pragma unroll
    for (int n = 0; n < 4; n++) {
      int f = col0 + wn * 64 + n * 16 + lm;
      float bias = b1[e * FFN + f];
#pragma unroll
      for (int r = 0; r < 4; r++) {
        int row = row0 + wm * 64 + m * 16 + lg * 4 + r;
        if (row < cnt) {
          float v = acc[m][n][r] + bias;
          H[(size_t)(base + row) * FFN + f] = f2bf(gelu_exact(v));
        }
      }
    }
  }
}

// GEMM2: contrib[p,d] = cw[p] * ( H[p,:] @ w2t[e]^T + b2[e] )   w2t: [D][F] bf16
__global__ __launch_bounds__(256) void k_gemm2(
    const ushort_t* __restrict__ H, const ushort_t* __restrict__ w2t, const float* __restrict__ b2,
    const int* __restrict__ counts, const int* __restrict__ offsets,
    const float* __restrict__ lwt, ushort_t* __restrict__ contrib) {
  int e = blockIdx.z;
  int cnt = counts[e];
  int xt, yt;
  xcd_decode(blockIdx.x, (T_TOK / BM) * (DIM / BN), T_TOK / BM, xt, yt);
  int row0 = xt * BM;
  if (row0 >= cnt) return;
  int base = offsets[e];
  int col0 = yt * BN;
  const ushort_t* Bt = w2t + (size_t)e * DIM * FFN;

  __shared__ __align__(16) ushort_t As[BM * BK];
  __shared__ __align__(16) ushort_t Bs[BM * BK];

  int tid = threadIdx.x;
  int wave = tid >> 6, lane = tid & 63;
  int wm = wave >> 1, wn = wave & 1;
  int lm = lane & 15, lg = lane >> 4;

  int srow = tid >> 2, seg = tid & 3;
  const ushort_t* asrc[2]; const ushort_t* bsrc[2];
#pragma unroll
  for (int j = 0; j < 2; j++) {
    int ar = min(row0 + j * 64 + srow, cnt - 1);
    asrc[j] = H + (size_t)(base + ar) * FFN + seg * 8;
    bsrc[j] = Bt + (size_t)(col0 + j * 64 + srow) * FFN + seg * 8;
  }
  f32x4 acc[4][4];
#pragma unroll
  for (int m = 0; m < 4; m++)
#pragma unroll
    for (int n = 0; n < 4; n++) acc[m][n] = (f32x4){0.f, 0.f, 0.f, 0.f};

  for (int k0 = 0; k0 < FFN; k0 += BK) {
#pragma unroll
    for (int j = 0; j < 2; j++) {
      gload16(asrc[j] + k0, &As[(j * 256 + wave * 64) * 8]);
      gload16(bsrc[j] + k0, &Bs[(j * 256 + wave * 64) * 8]);
    }
    __syncthreads();
    bf16x8 af[4], bfv[4];
#pragma unroll
    for (int m = 0; m < 4; m++)
      af[m] = *reinterpret_cast<const bf16x8*>(&As[(wm * 64 + m * 16 + lm) * BK + lg * 8]);
#pragma unroll
    for (int n = 0; n < 4; n++)
      bfv[n] = *reinterpret_cast<const bf16x8*>(&Bs[(wn * 64 + n * 16 + lm) * BK + lg * 8]);
#pragma unroll
    for (int m = 0; m < 4; m++)
#pragma unroll
      for (int n = 0; n < 4; n++)
        acc[m][n] = __builtin_amdgcn_mfma_f32_16x16x32_bf16(af[m], bfv[n], acc[m][n], 0, 0, 0);
    __syncthreads();
  }
#pragma unroll
  for (int m = 0; m < 4; m++) {
#pragma unroll
    for (int n = 0; n < 4; n++) {
      int d = col0 + wn * 64 + n * 16 + lm;
      float bias = b2[e * DIM + d];
#pragma unroll
      for (int r = 0; r < 4; r++) {
        int row = row0 + wm * 64 + m * 16 + lg * 4 + r;
        if (row < cnt) {
          float v = (acc[m][n][r] + bias) * lwt[base + row];
          contrib[(size_t)(base + row) * DIM + d] = f2bf(v);
        }
      }
    }
  }
}

// ---------------- combine: out = x + contrib[p0] + contrib[p1] ----------------
__global__ void k_combine(const float* __restrict__ x, const ushort_t* __restrict__ contrib,
                          const int* __restrict__ ppos, float* __restrict__ out) {
  int i = blockIdx.x * blockDim.x + threadIdx.x;
  int t = i / (DIM / 4);
  int dq = i % (DIM / 4);
  int p0 = ppos[t * 2 + 0], p1 = ppos[t * 2 + 1];
  float4 xv = reinterpret_cast<const float4*>(x)[i];
  ushort4v c0 = reinterpret_cast<const ushort4v*>(contrib + (size_t)p0 * DIM)[dq];
  ushort4v c1 = reinterpret_cast<const ushort4v*>(contrib + (size_t)p1 * DIM)[dq];
  float4 o;
  o.x = xv.x + bf2f(c0.x) + bf2f(c1.x);
  o.y = xv.y + bf2f(c0.y) + bf2f(c1.y);
  o.z = xv.z + bf2f(c0.z) + bf2f(c1.z);
  o.w = xv.w + bf2f(c0.w) + bf2f(c1.w);
  reinterpret_cast<float4*>(out)[i] = o;
}

extern "C" void kernel_launch(void* const* d_in, const int* in_sizes, int n_in,
                              void* d_out, int out_size, void* d_ws, size_t ws_size,
                              hipStream_t stream) {
  const float* x  = (const float*)d_in[0];
  const float* rw = (const float*)d_in[1];
  const float* w1 = (const float*)d_in[2];
  const float* b1 = (const float*)d_in[3];
  const float* w2 = (const float*)d_in[4];
  const float* b2 = (const float*)d_in[5];
  float* out = (float*)d_out;
  char* ws = (char*)d_ws;

  const size_t MB = 1u << 20;
  int*   counts  = (int*)(ws);
  int*   offsets = (int*)(ws + 64);
  int*   cursors = (int*)(ws + 128);
  int*   tidx    = (int*)(ws + 1 * MB);
  float* twt     = (float*)(ws + 2 * MB);
  int*   ltok    = (int*)(ws + 3 * MB);
  float* lwt     = (float*)(ws + 4 * MB);
  int*   ppos    = (int*)(ws + 5 * MB);
  // overlaid big buffers (lifetimes disjoint where they overlap):
  ushort_t* xbf     = (ushort_t*)(ws + 8 * MB);     // 32 MB, live cast..gemm1
  ushort_t* contrib = (ushort_t*)(ws + 8 * MB);     // 64 MB, live gemm2..combine (xbf dead)
  ushort_t* Hbuf    = (ushort_t*)(ws + 72 * MB);    // 256 MB, live gemm1..gemm2
  ushort_t* w1t     = (ushort_t*)(ws + 328 * MB);   // 256 MB, live wcvt1..gemm1
  ushort_t* w2t     = (ushort_t*)(ws + 328 * MB);   // 256 MB, live wcvt2..gemm2 (after gemm1)
  const size_t NEED = 584 * MB;
  if (ws_size < NEED) {
    hipMemsetAsync(d_out, 0, (size_t)out_size * sizeof(float), stream);
    return;
  }

  hipMemsetAsync(ws, 0, 256, stream);  // counts + cursors
  k_cast<<<dim3((T_TOK * (size_t)DIM / 4) / 256), 256, 0, stream>>>(x, xbf);
  k_router<<<T_TOK, 256, 0, stream>>>(x, rw, tidx, twt, counts);
  k_scan<<<1, 64, 0, stream>>>(counts, offsets);
  k_fill<<<T_TOK / 256, 256, 0, stream>>>(tidx, twt, offsets, cursors, ltok, lwt, ppos);
  // w1: [E][D][F] fp32 -> w1t [E][F][D] bf16
  k_wcvt<<<dim3(FFN / TT, DIM / TT, NE), 256, 0, stream>>>(w1, w1t, DIM, FFN);
  k_gemm1<<<dim3((T_TOK / BM) * (FFN / BN), 1, NE), 256, 0, stream>>>(xbf, w1t, b1, counts, offsets, ltok, Hbuf);
  // w2: [E][F][D] fp32 -> w2t [E][D][F] bf16  (after gemm1; reuses w1t region)
  k_wcvt<<<dim3(DIM / TT, FFN / TT, NE), 256, 0, stream>>>(w2, w2t, FFN, DIM);
  k_gemm2<<<dim3((T_TOK / BM) * (DIM / BN), 1, NE), 256, 0, stream>>>(Hbuf, w2t, b2, counts, offsets, lwt, contrib);
  k_combine<<<dim3((T_TOK * (size_t)DIM / 4) / 256), 256, 0, stream>>>(x, contrib, ppos, out);
}